// Round 4
// baseline (1624.882 us; speedup 1.0000x reference)
//
#include <hip/hip_runtime.h>
#include <stdint.h>

#define B_ 4
#define T_ 2048
#define C_ 1024
#define H_ 16
#define D_ 64
#define M_ (B_*T_)      /* 8192 */
#define K_ C_           /* 1024 */

typedef unsigned short ushort_t;
typedef __bf16 bf16x8 __attribute__((ext_vector_type(8)));
typedef float  float4_ __attribute__((ext_vector_type(4)));
typedef ushort_t ushort4_ __attribute__((ext_vector_type(4)));

__device__ __forceinline__ ushort_t f2bf(float f) {
    union { float f; uint32_t u; } c; c.f = f;
    uint32_t u = c.u;
    uint32_t r = (u + 0x7FFFu + ((u >> 16) & 1u)) >> 16;
    return (ushort_t)r;
}
__device__ __forceinline__ float4_ f4zero() { float4_ z; z[0]=0.f; z[1]=0.f; z[2]=0.f; z[3]=0.f; return z; }

// ---------------------------------------------------------------------------
// f32 -> bf16 conversion, 4 elements/thread
// ---------------------------------------------------------------------------
__global__ __launch_bounds__(256) void cvt_f32_bf16(const float* __restrict__ src,
                                                    ushort_t* __restrict__ dst) {
    const int i = (blockIdx.x * 256 + threadIdx.x) * 4;
    float4_ v = *(const float4_*)(src + i);
    ushort4_ o;
    #pragma unroll
    for (int e = 0; e < 4; e++) o[e] = f2bf(v[e]);
    *(ushort4_*)(dst + i) = o;
}

// ---------------------------------------------------------------------------
// w_o f32 [1024(hd)][1024(c)] -> wot bf16 [1024(c)][1024(hd)]
// ---------------------------------------------------------------------------
__global__ __launch_bounds__(256) void transpose_wo(const float* __restrict__ wo,
                                                    ushort_t* __restrict__ wot) {
    __shared__ ushort_t tile[64][65];
    const int c0 = (blockIdx.x & 15) * 64;
    const int r0 = (blockIdx.x >> 4) * 64;   // hd tile base
    const int tid = threadIdx.x;
    const int row = tid >> 2;                // 64 rows, 4 threads/row
    const int col = (tid & 3) * 16;
    #pragma unroll
    for (int r = 0; r < 4; r++) {
        float4_ v = *(const float4_*)(wo + (size_t)(r0 + row) * 1024 + c0 + col + r * 4);
        #pragma unroll
        for (int e = 0; e < 4; e++) tile[row][col + r * 4 + e] = f2bf(v[e]);
    }
    __syncthreads();
    #pragma unroll
    for (int r = 0; r < 2; r++) {
        bf16x8 v;
        #pragma unroll
        for (int e = 0; e < 8; e++) v[e] = __builtin_bit_cast(__bf16, tile[col + r * 8 + e][row]);
        *(bf16x8*)(wot + (size_t)(c0 + row) * 1024 + r0 + col + r * 8) = v;
    }
}

// ---------------------------------------------------------------------------
// GEMM: C[M x N] = A[M x K] * Bt[N x K]^T  (bf16 in, fp32 acc)
// MODE 0: Bt = Wcat [3072 x 1024]; epilogue scatters Q (x0.125) [nh][t][d],
//         K [nh][t][d], V transposed [nh][d][t]  (bf16 stores)
// MODE 1: Bt = wot [1024 x 1024]; plain *** f32 *** store to d_out
// ---------------------------------------------------------------------------
template<int MODE>
__global__ __launch_bounds__(256)
void gemm_bt(const ushort_t* __restrict__ A,
             const ushort_t* __restrict__ Bt,
             ushort_t* __restrict__ q_ws, ushort_t* __restrict__ k_ws,
             ushort_t* __restrict__ vt_ws, float* __restrict__ outp)
{
    __shared__ __align__(16) ushort_t As[128 * 32];
    __shared__ __align__(16) ushort_t Bs[128 * 32];
    const int tid = threadIdx.x;
    const int m0 = blockIdx.x * 128;
    const int n0 = blockIdx.y * 128;

    const int L    = tid & 63;
    const int wid  = tid >> 6;
    const int wr   = (wid >> 1) * 64;
    const int wc   = (wid & 1) * 64;
    const int quad = L >> 4;
    const int lc   = L & 15;

    float4_ acc[4][4];
    #pragma unroll
    for (int i = 0; i < 4; i++)
        #pragma unroll
        for (int j = 0; j < 4; j++) acc[i][j] = f4zero();

    const int off0 = tid * 16;   // byte offset into 8KB tile
    for (int k0 = 0; k0 < K_; k0 += 32) {
        __syncthreads();
        #pragma unroll
        for (int r = 0; r < 2; r++) {
            const int off = off0 + r * 4096;
            const int row = off >> 6;    // 64 B per tile row (32 bf16)
            const int col = off & 63;    // byte col
            bf16x8 va = *(const bf16x8*)((const char*)A  + (size_t)(m0 + row) * (K_ * 2) + k0 * 2 + col);
            bf16x8 vb = *(const bf16x8*)((const char*)Bt + (size_t)(n0 + row) * (K_ * 2) + k0 * 2 + col);
            *(bf16x8*)((char*)As + off) = va;
            *(bf16x8*)((char*)Bs + off) = vb;
        }
        __syncthreads();
        bf16x8 af[4], bfr[4];
        #pragma unroll
        for (int i = 0; i < 4; i++) {
            const int m = wr + i * 16 + lc;
            af[i]  = *(const bf16x8*)((const char*)As + m * 64 + quad * 16);
            const int n = wc + i * 16 + lc;
            bfr[i] = *(const bf16x8*)((const char*)Bs + n * 64 + quad * 16);
        }
        #pragma unroll
        for (int i = 0; i < 4; i++)
            #pragma unroll
            for (int j = 0; j < 4; j++)
                acc[i][j] = __builtin_amdgcn_mfma_f32_16x16x32_bf16(af[i], bfr[j], acc[i][j], 0, 0, 0);
    }

    // epilogue: C/D layout col=lane&15, row=quad*4+reg (m89-verified)
    const int mat = n0 >> 10;          // MODE 0: which of q/k/v
    const int nb  = n0 & 1023;
    #pragma unroll
    for (int i = 0; i < 4; i++) {
        #pragma unroll
        for (int j = 0; j < 4; j++) {
            #pragma unroll
            for (int rg = 0; rg < 4; rg++) {
                const int mg = m0 + wr + i * 16 + quad * 4 + rg;
                const float v = acc[i][j][rg];
                if (MODE == 1) {
                    const int cg = n0 + wc + j * 16 + lc;
                    outp[(size_t)mg * 1024 + cg] = v;          // f32 store (the fix)
                } else {
                    const int ln = nb + wc + j * 16 + lc;
                    const int h = ln >> 6, d = ln & 63;
                    const int n = mg >> 11, t = mg & 2047;
                    const int nh = n * H_ + h;
                    if (mat == 0)      q_ws [((size_t)nh * T_ + t) * 64 + d] = f2bf(v * 0.125f);
                    else if (mat == 1) k_ws [((size_t)nh * T_ + t) * 64 + d] = f2bf(v);
                    else               vt_ws[((size_t)nh * 64 + d) * T_ + t] = f2bf(v);
                }
            }
        }
    }
}

// ---------------------------------------------------------------------------
// DEBUG attention (kept frozen this round): vector-ALU flash attention,
// one thread per q-row. No MFMA, no shuffles, no layout assumptions.
// ---------------------------------------------------------------------------
__global__ __launch_bounds__(256)
void attn_simple(const ushort_t* __restrict__ q_ws, const ushort_t* __restrict__ k_ws,
                 const ushort_t* __restrict__ vt_ws, ushort_t* __restrict__ y_ws)
{
    __shared__ float Kf[64][64];   // [s][d]
    __shared__ float Vf[64][64];   // [s][d]
    const int tid = threadIdx.x;
    const int nh  = blockIdx.x;          // 0..63
    const int bt  = blockIdx.y;          // 0..7, 256 rows each
    const int t   = bt * 256 + tid;
    const int n   = nh >> 4, h = nh & 15;

    // load this row's q (already scaled by 0.125 at QKV epilogue)
    const ushort_t* qrow = q_ws + ((size_t)nh * T_ + t) * 64;
    float q[64], o[64];
    #pragma unroll
    for (int dq = 0; dq < 8; dq++) {
        bf16x8 v = *(const bf16x8*)(qrow + dq * 8);
        #pragma unroll
        for (int e = 0; e < 8; e++) q[dq * 8 + e] = (float)v[e];
    }
    #pragma unroll
    for (int d = 0; d < 64; d++) o[d] = 0.f;
    float m = -1e30f, l = 0.f;

    const ushort_t* kb = k_ws  + (size_t)nh * T_ * 64;   // [t][d]
    const ushort_t* vb = vt_ws + (size_t)nh * 64 * T_;   // [d][t]

    const int ntiles = bt * 4 + 4;
    for (int st = 0; st < ntiles; st++) {
        __syncthreads();
        {   // stage K tile [s][d] and V tile (transpose from [d][t]) as f32
            const int r  = tid >> 2;          // 0..63
            const int c0 = (tid & 3) * 16;    // 0,16,32,48
            bf16x8 ka = *(const bf16x8*)(kb + (size_t)(st * 64 + r) * 64 + c0);
            bf16x8 kb8 = *(const bf16x8*)(kb + (size_t)(st * 64 + r) * 64 + c0 + 8);
            #pragma unroll
            for (int e = 0; e < 8; e++) { Kf[r][c0 + e] = (float)ka[e]; Kf[r][c0 + 8 + e] = (float)kb8[e]; }
            bf16x8 va = *(const bf16x8*)(vb + (size_t)r * T_ + st * 64 + c0);
            bf16x8 vb8 = *(const bf16x8*)(vb + (size_t)r * T_ + st * 64 + c0 + 8);
            #pragma unroll
            for (int e = 0; e < 8; e++) { Vf[c0 + e][r] = (float)va[e]; Vf[c0 + 8 + e][r] = (float)vb8[e]; }
        }
        __syncthreads();

        for (int s = 0; s < 64; s++) {
            const int sg = st * 64 + s;
            if (sg <= t) {
                float dot = 0.f;
                #pragma unroll
                for (int d = 0; d < 64; d++) dot += q[d] * Kf[s][d];
                const float mn    = fmaxf(m, dot);
                const float p     = __expf(dot - mn);
                const float alpha = __expf(m - mn);
                l = l * alpha + p;
                m = mn;
                #pragma unroll
                for (int d = 0; d < 64; d++) o[d] = o[d] * alpha + p * Vf[s][d];
            }
        }
    }

    const float inv = 1.f / l;
    ushort_t* yrow = y_ws + ((size_t)(n * T_ + t)) * 1024 + h * 64;
    #pragma unroll
    for (int d = 0; d < 64; d++) yrow[d] = f2bf(o[d] * inv);
}

// ---------------------------------------------------------------------------
extern "C" void kernel_launch(void* const* d_in, const int* in_sizes, int n_in,
                              void* d_out, int out_size, void* d_ws, size_t ws_size,
                              hipStream_t stream) {
    (void)in_sizes; (void)n_in; (void)out_size; (void)ws_size;
    const float* x  = (const float*)d_in[0];
    const float* wq = (const float*)d_in[1];
    const float* wk = (const float*)d_in[2];
    const float* wv = (const float*)d_in[3];
    const float* wo = (const float*)d_in[4];
    char* ws = (char*)d_ws;
    const size_t MB = (size_t)1024 * 1024;
    ushort_t* x_bf  = (ushort_t*)(ws);            // 16 MB; reused as y after attn
    ushort_t* q_ws  = (ushort_t*)(ws + 16 * MB);  // 16 MB
    ushort_t* k_ws  = (ushort_t*)(ws + 32 * MB);  // 16 MB
    ushort_t* vt_ws = (ushort_t*)(ws + 48 * MB);  // 16 MB
    ushort_t* wcat  = (ushort_t*)(ws + 64 * MB);  // 6 MB  [3072][1024]
    ushort_t* wot   = (ushort_t*)(ws + 70 * MB);  // 2 MB  [1024(c)][1024(hd)]
    ushort_t* y_ws  = x_bf;                       // safe: attn never reads x_bf
    float*    outp  = (float*)d_out;              // f32 output (the fix)

    cvt_f32_bf16<<<dim3(8192), dim3(256), 0, stream>>>(x,  x_bf);
    cvt_f32_bf16<<<dim3(1024), dim3(256), 0, stream>>>(wq, wcat);
    cvt_f32_bf16<<<dim3(1024), dim3(256), 0, stream>>>(wk, wcat + 1024 * 1024);
    cvt_f32_bf16<<<dim3(1024), dim3(256), 0, stream>>>(wv, wcat + 2 * 1024 * 1024);
    transpose_wo<<<dim3(256), dim3(256), 0, stream>>>(wo, wot);
    gemm_bt<0><<<dim3(64, 24), dim3(256), 0, stream>>>(x_bf, wcat, q_ws, k_ws, vt_ws, nullptr);
    attn_simple<<<dim3(64, 8), dim3(256), 0, stream>>>(q_ws, k_ws, vt_ws, y_ws);
    gemm_bt<1><<<dim3(64, 8), dim3(256), 0, stream>>>(y_ws, wot, nullptr, nullptr, nullptr, outp);
}

// Round 5
// 431.271 us; speedup vs baseline: 3.7677x; 3.7677x over previous
//
#include <hip/hip_runtime.h>
#include <stdint.h>

#define B_ 4
#define T_ 2048
#define C_ 1024
#define H_ 16
#define D_ 64
#define M_ (B_*T_)      /* 8192 */
#define K_ C_           /* 1024 */

typedef unsigned short ushort_t;
typedef __bf16 bf16x8 __attribute__((ext_vector_type(8)));
typedef float  float4_ __attribute__((ext_vector_type(4)));
typedef ushort_t ushort4_ __attribute__((ext_vector_type(4)));

__device__ __forceinline__ ushort_t f2bf(float f) {
    union { float f; uint32_t u; } c; c.f = f;
    uint32_t u = c.u;
    uint32_t r = (u + 0x7FFFu + ((u >> 16) & 1u)) >> 16;
    return (ushort_t)r;
}
__device__ __forceinline__ float4_ f4zero() { float4_ z; z[0]=0.f; z[1]=0.f; z[2]=0.f; z[3]=0.f; return z; }

// ---------------------------------------------------------------------------
// f32 -> bf16 conversion, 4 elements/thread
// ---------------------------------------------------------------------------
__global__ __launch_bounds__(256) void cvt_f32_bf16(const float* __restrict__ src,
                                                    ushort_t* __restrict__ dst) {
    const int i = (blockIdx.x * 256 + threadIdx.x) * 4;
    float4_ v = *(const float4_*)(src + i);
    ushort4_ o;
    #pragma unroll
    for (int e = 0; e < 4; e++) o[e] = f2bf(v[e]);
    *(ushort4_*)(dst + i) = o;
}

// ---------------------------------------------------------------------------
// w_o f32 [1024(hd)][1024(c)] -> wot bf16 [1024(c)][1024(hd)]
// ---------------------------------------------------------------------------
__global__ __launch_bounds__(256) void transpose_wo(const float* __restrict__ wo,
                                                    ushort_t* __restrict__ wot) {
    __shared__ ushort_t tile[64][65];
    const int c0 = (blockIdx.x & 15) * 64;
    const int r0 = (blockIdx.x >> 4) * 64;   // hd tile base
    const int tid = threadIdx.x;
    const int row = tid >> 2;                // 64 rows, 4 threads/row
    const int col = (tid & 3) * 16;
    #pragma unroll
    for (int r = 0; r < 4; r++) {
        float4_ v = *(const float4_*)(wo + (size_t)(r0 + row) * 1024 + c0 + col + r * 4);
        #pragma unroll
        for (int e = 0; e < 4; e++) tile[row][col + r * 4 + e] = f2bf(v[e]);
    }
    __syncthreads();
    #pragma unroll
    for (int r = 0; r < 2; r++) {
        bf16x8 v;
        #pragma unroll
        for (int e = 0; e < 8; e++) v[e] = __builtin_bit_cast(__bf16, tile[col + r * 8 + e][row]);
        *(bf16x8*)(wot + (size_t)(c0 + row) * 1024 + r0 + col + r * 8) = v;
    }
}

// ---------------------------------------------------------------------------
// GEMM: C[M x N] = A[M x K] * Bt[N x K]^T  (bf16 in, fp32 acc)
// MODE 0: Bt = Wcat [3072 x 1024]; epilogue scatters Q (x0.125) [nh][t][d],
//         K [nh][t][d], V transposed [nh][d][t]  (bf16 stores)
// MODE 1: Bt = wot [1024 x 1024]; f32 store to d_out
// (frozen — validated round 4)
// ---------------------------------------------------------------------------
template<int MODE>
__global__ __launch_bounds__(256)
void gemm_bt(const ushort_t* __restrict__ A,
             const ushort_t* __restrict__ Bt,
             ushort_t* __restrict__ q_ws, ushort_t* __restrict__ k_ws,
             ushort_t* __restrict__ vt_ws, float* __restrict__ outp)
{
    __shared__ __align__(16) ushort_t As[128 * 32];
    __shared__ __align__(16) ushort_t Bs[128 * 32];
    const int tid = threadIdx.x;
    const int m0 = blockIdx.x * 128;
    const int n0 = blockIdx.y * 128;

    const int L    = tid & 63;
    const int wid  = tid >> 6;
    const int wr   = (wid >> 1) * 64;
    const int wc   = (wid & 1) * 64;
    const int quad = L >> 4;
    const int lc   = L & 15;

    float4_ acc[4][4];
    #pragma unroll
    for (int i = 0; i < 4; i++)
        #pragma unroll
        for (int j = 0; j < 4; j++) acc[i][j] = f4zero();

    const int off0 = tid * 16;   // byte offset into 8KB tile
    for (int k0 = 0; k0 < K_; k0 += 32) {
        __syncthreads();
        #pragma unroll
        for (int r = 0; r < 2; r++) {
            const int off = off0 + r * 4096;
            const int row = off >> 6;    // 64 B per tile row (32 bf16)
            const int col = off & 63;    // byte col
            bf16x8 va = *(const bf16x8*)((const char*)A  + (size_t)(m0 + row) * (K_ * 2) + k0 * 2 + col);
            bf16x8 vb = *(const bf16x8*)((const char*)Bt + (size_t)(n0 + row) * (K_ * 2) + k0 * 2 + col);
            *(bf16x8*)((char*)As + off) = va;
            *(bf16x8*)((char*)Bs + off) = vb;
        }
        __syncthreads();
        bf16x8 af[4], bfr[4];
        #pragma unroll
        for (int i = 0; i < 4; i++) {
            const int m = wr + i * 16 + lc;
            af[i]  = *(const bf16x8*)((const char*)As + m * 64 + quad * 16);
            const int n = wc + i * 16 + lc;
            bfr[i] = *(const bf16x8*)((const char*)Bs + n * 64 + quad * 16);
        }
        #pragma unroll
        for (int i = 0; i < 4; i++)
            #pragma unroll
            for (int j = 0; j < 4; j++)
                acc[i][j] = __builtin_amdgcn_mfma_f32_16x16x32_bf16(af[i], bfr[j], acc[i][j], 0, 0, 0);
    }

    // epilogue: C/D layout col=lane&15, row=quad*4+reg (m89-verified)
    const int mat = n0 >> 10;          // MODE 0: which of q/k/v
    const int nb  = n0 & 1023;
    #pragma unroll
    for (int i = 0; i < 4; i++) {
        #pragma unroll
        for (int j = 0; j < 4; j++) {
            #pragma unroll
            for (int rg = 0; rg < 4; rg++) {
                const int mg = m0 + wr + i * 16 + quad * 4 + rg;
                const float v = acc[i][j][rg];
                if (MODE == 1) {
                    const int cg = n0 + wc + j * 16 + lc;
                    outp[(size_t)mg * 1024 + cg] = v;          // f32 store
                } else {
                    const int ln = nb + wc + j * 16 + lc;
                    const int h = ln >> 6, d = ln & 63;
                    const int n = mg >> 11, t = mg & 2047;
                    const int nh = n * H_ + h;
                    if (mat == 0)      q_ws [((size_t)nh * T_ + t) * 64 + d] = f2bf(v * 0.125f);
                    else if (mat == 1) k_ws [((size_t)nh * T_ + t) * 64 + d] = f2bf(v);
                    else               vt_ws[((size_t)nh * 64 + d) * T_ + t] = f2bf(v);
                }
            }
        }
    }
}

// ---------------------------------------------------------------------------
// MFMA flash attention: 1 block = (n,h, 64-row q-tile); 4 waves x 16 q-rows.
// LDS rows padded to 72 elements (144 B) so quad-strided ds_read_b128 is
// 2-way (free) instead of 16-way (5.7x, m136).
// ---------------------------------------------------------------------------
#define KP 72   /* padded row pitch, elements */

__global__ __launch_bounds__(256)
void attn(const ushort_t* __restrict__ q_ws, const ushort_t* __restrict__ k_ws,
          const ushort_t* __restrict__ vt_ws, ushort_t* __restrict__ y_ws)
{
    __shared__ __align__(16) ushort_t Ks[64 * KP];      // [s][d], padded
    __shared__ __align__(16) ushort_t Vs[64 * KP];      // [d][s], padded
    __shared__ __align__(16) ushort_t Ps[4][16 * KP];   // per-wave P [m][s], padded
    const int tid  = threadIdx.x;
    const int L    = tid & 63;
    const int w    = tid >> 6;
    const int quad = L >> 4, lc = L & 15;
    const int bid  = blockIdx.x;
    const int qt   = bid & 31;
    const int nh   = bid >> 5;
    const int n    = nh >> 4;
    const int tq0  = qt * 64 + w * 16;

    // Q fragments (A-layout): row tq0+lc, k = quad*8+e (+32)
    const ushort_t* qbase = q_ws + ((size_t)nh * T_ + tq0) * 64;
    const bf16x8 qf0 = *(const bf16x8*)(qbase + (size_t)lc * 64 + quad * 8);
    const bf16x8 qf1 = *(const bf16x8*)(qbase + (size_t)lc * 64 + quad * 8 + 32);

    float m_i[4], l_i[4];
    float4_ o[4];
    #pragma unroll
    for (int r = 0; r < 4; r++) { m_i[r] = -1e30f; l_i[r] = 0.f; o[r] = f4zero(); }

    const ushort_t* kbase = k_ws  + (size_t)nh * T_ * 64;   // [t][d]
    const ushort_t* vbase = vt_ws + (size_t)nh * 64 * T_;   // [d][t]

    for (int st = 0; st <= qt; st++) {
        // stage K [s][d] and Vt [d][s] tiles; each thread 16 B x2 per array
        #pragma unroll
        for (int r = 0; r < 2; r++) {
            const int off = tid * 16 + r * 4096;   // logical offset in 64x128B tile
            const int row = off >> 7;
            const int col = off & 127;
            bf16x8 kv = *(const bf16x8*)((const char*)kbase + (size_t)(st * 64 + row) * 128 + col);
            bf16x8 vv = *(const bf16x8*)((const char*)vbase + (size_t)row * (T_ * 2) + st * 128 + col);
            *(bf16x8*)((char*)Ks + row * (KP * 2) + col) = kv;
            *(bf16x8*)((char*)Vs + row * (KP * 2) + col) = vv;
        }
        __syncthreads();

        // S = Q K^T, 4 col-blocks of 16 s
        float4_ s[4];
        #pragma unroll
        for (int j = 0; j < 4; j++) {
            const int srow = j * 16 + lc;
            const bf16x8 b0 = *(const bf16x8*)((const char*)Ks + srow * (KP * 2) + quad * 16);
            const bf16x8 b1 = *(const bf16x8*)((const char*)Ks + srow * (KP * 2) + 64 + quad * 16);
            float4_ a = f4zero();
            a = __builtin_amdgcn_mfma_f32_16x16x32_bf16(qf0, b0, a, 0, 0, 0);
            a = __builtin_amdgcn_mfma_f32_16x16x32_bf16(qf1, b1, a, 0, 0, 0);
            s[j] = a;
        }
        if (st == qt) {   // causal mask on diagonal tile
            #pragma unroll
            for (int j = 0; j < 4; j++)
                #pragma unroll
                for (int rg = 0; rg < 4; rg++) {
                    const int tg = tq0 + quad * 4 + rg;
                    const int sg = st * 64 + j * 16 + lc;
                    if (sg > tg) s[j][rg] = -1e30f;
                }
        }
        // online softmax; row = quad*4+rg, cols across the quad's 16 lanes
        #pragma unroll
        for (int rg = 0; rg < 4; rg++) {
            float rm = fmaxf(fmaxf(s[0][rg], s[1][rg]), fmaxf(s[2][rg], s[3][rg]));
            #pragma unroll
            for (int d = 1; d < 16; d <<= 1) rm = fmaxf(rm, __shfl_xor(rm, d, 16));
            const float mn = fmaxf(m_i[rg], rm);
            const float alpha = __expf(m_i[rg] - mn);
            float rs = 0.f;
            #pragma unroll
            for (int j = 0; j < 4; j++) { const float p = __expf(s[j][rg] - mn); s[j][rg] = p; rs += p; }
            #pragma unroll
            for (int d = 1; d < 16; d <<= 1) rs += __shfl_xor(rs, d, 16);
            l_i[rg] = l_i[rg] * alpha + rs;
            m_i[rg] = mn;
            #pragma unroll
            for (int db = 0; db < 4; db++) o[db][rg] *= alpha;
        }
        // P -> LDS [m][s] (C-layout -> A-layout round trip, m120 pattern)
        ushort_t* pw = Ps[w];
        #pragma unroll
        for (int j = 0; j < 4; j++)
            #pragma unroll
            for (int rg = 0; rg < 4; rg++)
                pw[(quad * 4 + rg) * KP + j * 16 + lc] = f2bf(s[j][rg]);

        // PV: O[m][d] += P[m][s] * Vt[d][s]^T
        const bf16x8 pa0 = *(const bf16x8*)((const char*)pw + lc * (KP * 2) + quad * 16);
        const bf16x8 pa1 = *(const bf16x8*)((const char*)pw + lc * (KP * 2) + 64 + quad * 16);
        #pragma unroll
        for (int db = 0; db < 4; db++) {
            const int d = db * 16 + lc;
            const bf16x8 vb0 = *(const bf16x8*)((const char*)Vs + d * (KP * 2) + quad * 16);
            const bf16x8 vb1 = *(const bf16x8*)((const char*)Vs + d * (KP * 2) + 64 + quad * 16);
            o[db] = __builtin_amdgcn_mfma_f32_16x16x32_bf16(pa0, vb0, o[db], 0, 0, 0);
            o[db] = __builtin_amdgcn_mfma_f32_16x16x32_bf16(pa1, vb1, o[db], 0, 0, 0);
        }
        __syncthreads();   // all waves done with Ks/Vs before next stage
    }

    // epilogue: y[n*T+t][h*64+d]
    const int h = nh & 15;
    #pragma unroll
    for (int db = 0; db < 4; db++) {
        #pragma unroll
        for (int rg = 0; rg < 4; rg++) {
            const int t = tq0 + quad * 4 + rg;
            const int d = db * 16 + lc;
            const float v = o[db][rg] / l_i[rg];
            y_ws[(size_t)(n * T_ + t) * 1024 + h * 64 + d] = f2bf(v);
        }
    }
}

// ---------------------------------------------------------------------------
extern "C" void kernel_launch(void* const* d_in, const int* in_sizes, int n_in,
                              void* d_out, int out_size, void* d_ws, size_t ws_size,
                              hipStream_t stream) {
    (void)in_sizes; (void)n_in; (void)out_size; (void)ws_size;
    const float* x  = (const float*)d_in[0];
    const float* wq = (const float*)d_in[1];
    const float* wk = (const float*)d_in[2];
    const float* wv = (const float*)d_in[3];
    const float* wo = (const float*)d_in[4];
    char* ws = (char*)d_ws;
    const size_t MB = (size_t)1024 * 1024;
    ushort_t* x_bf  = (ushort_t*)(ws);            // 16 MB; reused as y after attn
    ushort_t* q_ws  = (ushort_t*)(ws + 16 * MB);  // 16 MB
    ushort_t* k_ws  = (ushort_t*)(ws + 32 * MB);  // 16 MB
    ushort_t* vt_ws = (ushort_t*)(ws + 48 * MB);  // 16 MB
    ushort_t* wcat  = (ushort_t*)(ws + 64 * MB);  // 6 MB  [3072][1024]
    ushort_t* wot   = (ushort_t*)(ws + 70 * MB);  // 2 MB  [1024(c)][1024(hd)]
    ushort_t* y_ws  = x_bf;                       // safe: attn never reads x_bf
    float*    outp  = (float*)d_out;              // f32 output

    cvt_f32_bf16<<<dim3(8192), dim3(256), 0, stream>>>(x,  x_bf);
    cvt_f32_bf16<<<dim3(1024), dim3(256), 0, stream>>>(wq, wcat);
    cvt_f32_bf16<<<dim3(1024), dim3(256), 0, stream>>>(wk, wcat + 1024 * 1024);
    cvt_f32_bf16<<<dim3(1024), dim3(256), 0, stream>>>(wv, wcat + 2 * 1024 * 1024);
    transpose_wo<<<dim3(256), dim3(256), 0, stream>>>(wo, wot);
    gemm_bt<0><<<dim3(64, 24), dim3(256), 0, stream>>>(x_bf, wcat, q_ws, k_ws, vt_ws, nullptr);
    attn<<<dim3(2048), dim3(256), 0, stream>>>(q_ws, k_ws, vt_ws, y_ws);
    gemm_bt<1><<<dim3(64, 8), dim3(256), 0, stream>>>(y_ws, wot, nullptr, nullptr, nullptr, outp);
}

// Round 6
// 343.854 us; speedup vs baseline: 4.7255x; 1.2542x over previous
//
#include <hip/hip_runtime.h>
#include <stdint.h>

#define B_ 4
#define T_ 2048
#define C_ 1024
#define H_ 16
#define D_ 64
#define M_ (B_*T_)      /* 8192 */
#define K_ C_           /* 1024 */

typedef unsigned short ushort_t;
typedef __bf16 bf16x8 __attribute__((ext_vector_type(8)));
typedef float  float4_ __attribute__((ext_vector_type(4)));
typedef ushort_t ushort4_ __attribute__((ext_vector_type(4)));

__device__ __forceinline__ ushort_t f2bf(float f) {
    union { float f; uint32_t u; } c; c.f = f;
    uint32_t u = c.u;
    uint32_t r = (u + 0x7FFFu + ((u >> 16) & 1u)) >> 16;
    return (ushort_t)r;
}
__device__ __forceinline__ float4_ f4zero() { float4_ z; z[0]=0.f; z[1]=0.f; z[2]=0.f; z[3]=0.f; return z; }

// ---------------------------------------------------------------------------
// f32 -> bf16 conversion, 4 elements/thread
// ---------------------------------------------------------------------------
__global__ __launch_bounds__(256) void cvt_f32_bf16(const float* __restrict__ src,
                                                    ushort_t* __restrict__ dst) {
    const int i = (blockIdx.x * 256 + threadIdx.x) * 4;
    float4_ v = *(const float4_*)(src + i);
    ushort4_ o;
    #pragma unroll
    for (int e = 0; e < 4; e++) o[e] = f2bf(v[e]);
    *(ushort4_*)(dst + i) = o;
}

// ---------------------------------------------------------------------------
// w_o f32 [1024(hd)][1024(c)] -> wot bf16 [1024(c)][1024(hd)]
// ---------------------------------------------------------------------------
__global__ __launch_bounds__(256) void transpose_wo(const float* __restrict__ wo,
                                                    ushort_t* __restrict__ wot) {
    __shared__ ushort_t tile[64][65];
    const int c0 = (blockIdx.x & 15) * 64;
    const int r0 = (blockIdx.x >> 4) * 64;   // hd tile base
    const int tid = threadIdx.x;
    const int row = tid >> 2;                // 64 rows, 4 threads/row
    const int col = (tid & 3) * 16;
    #pragma unroll
    for (int r = 0; r < 4; r++) {
        float4_ v = *(const float4_*)(wo + (size_t)(r0 + row) * 1024 + c0 + col + r * 4);
        #pragma unroll
        for (int e = 0; e < 4; e++) tile[row][col + r * 4 + e] = f2bf(v[e]);
    }
    __syncthreads();
    #pragma unroll
    for (int r = 0; r < 2; r++) {
        bf16x8 v;
        #pragma unroll
        for (int e = 0; e < 8; e++) v[e] = __builtin_bit_cast(__bf16, tile[col + r * 8 + e][row]);
        *(bf16x8*)(wot + (size_t)(c0 + row) * 1024 + r0 + col + r * 8) = v;
    }
}

// ---------------------------------------------------------------------------
// GEMM: C[M x N] = A[M x K] * Bt[N x K]^T  (bf16 in, fp32 acc)
// MODE 0: Bt = Wcat [3072 x 1024]; epilogue scatters Q (x0.125) [nh][t][d],
//         K [nh][t][d], V transposed [nh][d][t]  (bf16 stores)
// MODE 1: Bt = wot [1024 x 1024]; f32 store to d_out
// (frozen — validated rounds 4/5)
// ---------------------------------------------------------------------------
template<int MODE>
__global__ __launch_bounds__(256)
void gemm_bt(const ushort_t* __restrict__ A,
             const ushort_t* __restrict__ Bt,
             ushort_t* __restrict__ q_ws, ushort_t* __restrict__ k_ws,
             ushort_t* __restrict__ vt_ws, float* __restrict__ outp)
{
    __shared__ __align__(16) ushort_t As[128 * 32];
    __shared__ __align__(16) ushort_t Bs[128 * 32];
    const int tid = threadIdx.x;
    const int m0 = blockIdx.x * 128;
    const int n0 = blockIdx.y * 128;

    const int L    = tid & 63;
    const int wid  = tid >> 6;
    const int wr   = (wid >> 1) * 64;
    const int wc   = (wid & 1) * 64;
    const int quad = L >> 4;
    const int lc   = L & 15;

    float4_ acc[4][4];
    #pragma unroll
    for (int i = 0; i < 4; i++)
        #pragma unroll
        for (int j = 0; j < 4; j++) acc[i][j] = f4zero();

    const int off0 = tid * 16;   // byte offset into 8KB tile
    for (int k0 = 0; k0 < K_; k0 += 32) {
        __syncthreads();
        #pragma unroll
        for (int r = 0; r < 2; r++) {
            const int off = off0 + r * 4096;
            const int row = off >> 6;    // 64 B per tile row (32 bf16)
            const int col = off & 63;    // byte col
            bf16x8 va = *(const bf16x8*)((const char*)A  + (size_t)(m0 + row) * (K_ * 2) + k0 * 2 + col);
            bf16x8 vb = *(const bf16x8*)((const char*)Bt + (size_t)(n0 + row) * (K_ * 2) + k0 * 2 + col);
            *(bf16x8*)((char*)As + off) = va;
            *(bf16x8*)((char*)Bs + off) = vb;
        }
        __syncthreads();
        bf16x8 af[4], bfr[4];
        #pragma unroll
        for (int i = 0; i < 4; i++) {
            const int m = wr + i * 16 + lc;
            af[i]  = *(const bf16x8*)((const char*)As + m * 64 + quad * 16);
            const int n = wc + i * 16 + lc;
            bfr[i] = *(const bf16x8*)((const char*)Bs + n * 64 + quad * 16);
        }
        #pragma unroll
        for (int i = 0; i < 4; i++)
            #pragma unroll
            for (int j = 0; j < 4; j++)
                acc[i][j] = __builtin_amdgcn_mfma_f32_16x16x32_bf16(af[i], bfr[j], acc[i][j], 0, 0, 0);
    }

    // epilogue: C/D layout col=lane&15, row=quad*4+reg (m89-verified)
    const int mat = n0 >> 10;          // MODE 0: which of q/k/v
    const int nb  = n0 & 1023;
    #pragma unroll
    for (int i = 0; i < 4; i++) {
        #pragma unroll
        for (int j = 0; j < 4; j++) {
            #pragma unroll
            for (int rg = 0; rg < 4; rg++) {
                const int mg = m0 + wr + i * 16 + quad * 4 + rg;
                const float v = acc[i][j][rg];
                if (MODE == 1) {
                    const int cg = n0 + wc + j * 16 + lc;
                    outp[(size_t)mg * 1024 + cg] = v;          // f32 store
                } else {
                    const int ln = nb + wc + j * 16 + lc;
                    const int h = ln >> 6, d = ln & 63;
                    const int n = mg >> 11, t = mg & 2047;
                    const int nh = n * H_ + h;
                    if (mat == 0)      q_ws [((size_t)nh * T_ + t) * 64 + d] = f2bf(v * 0.125f);
                    else if (mat == 1) k_ws [((size_t)nh * T_ + t) * 64 + d] = f2bf(v);
                    else               vt_ws[((size_t)nh * 64 + d) * T_ + t] = f2bf(v);
                }
            }
        }
    }
}

// ---------------------------------------------------------------------------
// MFMA flash attention, TRANSPOSED formulation:
//   S^T = K Q^T  (A = K-tile rows, B = Q rows)  -> lane owns q-row t = lane&15
//   O^T = V^T P^T (A = V^T rows,  B = P^T rows) -> per-lane scalar m/l softmax
// 1 block = (n,h, 64-row q-tile); 4 waves x 16 q-rows. LDS pitch 72 (pad).
// ---------------------------------------------------------------------------
#define KP 72   /* padded row pitch, elements */

__global__ __launch_bounds__(256)
void attn(const ushort_t* __restrict__ q_ws, const ushort_t* __restrict__ k_ws,
          const ushort_t* __restrict__ vt_ws, ushort_t* __restrict__ y_ws)
{
    __shared__ __align__(16) ushort_t Ks[64 * KP];      // [s][d], padded
    __shared__ __align__(16) ushort_t Vs[64 * KP];      // [d][s], padded
    __shared__ __align__(16) ushort_t Ps[4][16 * KP];   // per-wave P^T as [t][s]
    const int tid  = threadIdx.x;
    const int L    = tid & 63;
    const int w    = tid >> 6;
    const int quad = L >> 4, lc = L & 15;
    const int bid  = blockIdx.x;
    const int qt   = 31 - (bid & 31);    // heavy blocks first (tail balance)
    const int nh   = bid >> 5;
    const int n    = nh >> 4;
    const int tq0  = qt * 64 + w * 16;
    const int tg   = tq0 + lc;           // this lane's q-row

    // Q fragments (B-operand layout [n=t=lc][k=d=quad*8+j]):
    const ushort_t* qbase = q_ws + ((size_t)nh * T_ + tq0) * 64;
    const bf16x8 qf0 = *(const bf16x8*)(qbase + (size_t)lc * 64 + quad * 8);
    const bf16x8 qf1 = *(const bf16x8*)(qbase + (size_t)lc * 64 + quad * 8 + 32);

    float m_i = -1e30f, l_i = 0.f;       // per-lane scalars (q-row tg)
    float4_ o[4];                        // O^T C-layout: col=t (lane), row=d
    #pragma unroll
    for (int r = 0; r < 4; r++) o[r] = f4zero();

    const ushort_t* kbase = k_ws  + (size_t)nh * T_ * 64;   // [t][d]
    const ushort_t* vbase = vt_ws + (size_t)nh * 64 * T_;   // [d][t]
    ushort_t* pw = Ps[w];

    for (int st = 0; st <= qt; st++) {
        // stage K [s][d] and Vt [d][s] tiles; each thread 16 B x2 per array
        #pragma unroll
        for (int r = 0; r < 2; r++) {
            const int off = tid * 16 + r * 4096;   // logical offset in 64x128B tile
            const int row = off >> 7;
            const int col = off & 127;
            bf16x8 kv = *(const bf16x8*)((const char*)kbase + (size_t)(st * 64 + row) * 128 + col);
            bf16x8 vv = *(const bf16x8*)((const char*)vbase + (size_t)row * (T_ * 2) + st * 128 + col);
            *(bf16x8*)((char*)Ks + row * (KP * 2) + col) = kv;
            *(bf16x8*)((char*)Vs + row * (KP * 2) + col) = vv;
        }
        __syncthreads();

        // S^T = K Q^T: 4 s-blocks of 16; D[s][t]: row=quad*4+rg -> s, col=lc -> t
        float4_ s[4];
        #pragma unroll
        for (int sb = 0; sb < 4; sb++) {
            const int srow = sb * 16 + lc;
            const bf16x8 kf0 = *(const bf16x8*)((const char*)Ks + srow * (KP * 2) + quad * 16);
            const bf16x8 kf1 = *(const bf16x8*)((const char*)Ks + srow * (KP * 2) + 64 + quad * 16);
            float4_ a = f4zero();
            a = __builtin_amdgcn_mfma_f32_16x16x32_bf16(kf0, qf0, a, 0, 0, 0);
            a = __builtin_amdgcn_mfma_f32_16x16x32_bf16(kf1, qf1, a, 0, 0, 0);
            s[sb] = a;
        }
        if (st == qt) {   // causal mask on diagonal tile: s_global > t_global
            #pragma unroll
            for (int sb = 0; sb < 4; sb++)
                #pragma unroll
                for (int rg = 0; rg < 4; rg++) {
                    const int sg = st * 64 + sb * 16 + quad * 4 + rg;
                    if (sg > tg) s[sb][rg] = -1e30f;
                }
        }
        // online softmax, per-lane: 16 in-register scores for q-row tg
        float rm = -1e30f;
        #pragma unroll
        for (int sb = 0; sb < 4; sb++)
            #pragma unroll
            for (int rg = 0; rg < 4; rg++) rm = fmaxf(rm, s[sb][rg]);
        rm = fmaxf(rm, __shfl_xor(rm, 16));
        rm = fmaxf(rm, __shfl_xor(rm, 32));
        const float mn    = fmaxf(m_i, rm);
        const float alpha = __expf(m_i - mn);
        float rs = 0.f;
        #pragma unroll
        for (int sb = 0; sb < 4; sb++)
            #pragma unroll
            for (int rg = 0; rg < 4; rg++) {
                const float p = __expf(s[sb][rg] - mn);
                s[sb][rg] = p;
                rs += p;
            }
        rs += __shfl_xor(rs, 16);
        rs += __shfl_xor(rs, 32);
        l_i = l_i * alpha + rs;
        m_i = mn;
        #pragma unroll
        for (int db = 0; db < 4; db++)
            #pragma unroll
            for (int rg = 0; rg < 4; rg++) o[db][rg] *= alpha;

        // P^T -> LDS as [t][s] (C->B layout round trip)
        #pragma unroll
        for (int sb = 0; sb < 4; sb++)
            #pragma unroll
            for (int rg = 0; rg < 4; rg++)
                pw[lc * KP + sb * 16 + quad * 4 + rg] = f2bf(s[sb][rg]);

        // O^T += V^T P^T: A = Vs row d [k=s], B = Pb row t [k=s]
        const bf16x8 pa0 = *(const bf16x8*)((const char*)pw + lc * (KP * 2) + quad * 16);
        const bf16x8 pa1 = *(const bf16x8*)((const char*)pw + lc * (KP * 2) + 64 + quad * 16);
        #pragma unroll
        for (int db = 0; db < 4; db++) {
            const int d = db * 16 + lc;
            const bf16x8 vf0 = *(const bf16x8*)((const char*)Vs + d * (KP * 2) + quad * 16);
            const bf16x8 vf1 = *(const bf16x8*)((const char*)Vs + d * (KP * 2) + 64 + quad * 16);
            o[db] = __builtin_amdgcn_mfma_f32_16x16x32_bf16(vf0, pa0, o[db], 0, 0, 0);
            o[db] = __builtin_amdgcn_mfma_f32_16x16x32_bf16(vf1, pa1, o[db], 0, 0, 0);
        }
        __syncthreads();   // all waves done with Ks/Vs before next stage
    }

    // epilogue: O^T lane owns q-row tg; d = db*16 + quad*4 + rg (4 consecutive)
    const int h = nh & 15;
    const float inv = 1.f / l_i;
    ushort_t* yrow = y_ws + ((size_t)(n * T_ + tg)) * 1024 + h * 64;
    #pragma unroll
    for (int db = 0; db < 4; db++) {
        ushort4_ pk;
        #pragma unroll
        for (int rg = 0; rg < 4; rg++) pk[rg] = f2bf(o[db][rg] * inv);
        *(ushort4_*)(yrow + db * 16 + quad * 4) = pk;
    }
}

// ---------------------------------------------------------------------------
extern "C" void kernel_launch(void* const* d_in, const int* in_sizes, int n_in,
                              void* d_out, int out_size, void* d_ws, size_t ws_size,
                              hipStream_t stream) {
    (void)in_sizes; (void)n_in; (void)out_size; (void)ws_size;
    const float* x  = (const float*)d_in[0];
    const float* wq = (const float*)d_in[1];
    const float* wk = (const float*)d_in[2];
    const float* wv = (const float*)d_in[3];
    const float* wo = (const float*)d_in[4];
    char* ws = (char*)d_ws;
    const size_t MB = (size_t)1024 * 1024;
    ushort_t* x_bf  = (ushort_t*)(ws);            // 16 MB; reused as y after attn
    ushort_t* q_ws  = (ushort_t*)(ws + 16 * MB);  // 16 MB
    ushort_t* k_ws  = (ushort_t*)(ws + 32 * MB);  // 16 MB
    ushort_t* vt_ws = (ushort_t*)(ws + 48 * MB);  // 16 MB
    ushort_t* wcat  = (ushort_t*)(ws + 64 * MB);  // 6 MB  [3072][1024]
    ushort_t* wot   = (ushort_t*)(ws + 70 * MB);  // 2 MB  [1024(c)][1024(hd)]
    ushort_t* y_ws  = x_bf;                       // safe: attn never reads x_bf
    float*    outp  = (float*)d_out;              // f32 output

    cvt_f32_bf16<<<dim3(8192), dim3(256), 0, stream>>>(x,  x_bf);
    cvt_f32_bf16<<<dim3(1024), dim3(256), 0, stream>>>(wq, wcat);
    cvt_f32_bf16<<<dim3(1024), dim3(256), 0, stream>>>(wk, wcat + 1024 * 1024);
    cvt_f32_bf16<<<dim3(1024), dim3(256), 0, stream>>>(wv, wcat + 2 * 1024 * 1024);
    transpose_wo<<<dim3(256), dim3(256), 0, stream>>>(wo, wot);
    gemm_bt<0><<<dim3(64, 24), dim3(256), 0, stream>>>(x_bf, wcat, q_ws, k_ws, vt_ws, nullptr);
    attn<<<dim3(2048), dim3(256), 0, stream>>>(q_ws, k_ws, vt_ws, y_ws);
    gemm_bt<1><<<dim3(64, 8), dim3(256), 0, stream>>>(y_ws, wot, nullptr, nullptr, nullptr, outp);
}

// Round 7
// 339.902 us; speedup vs baseline: 4.7804x; 1.0116x over previous
//
#include <hip/hip_runtime.h>
#include <stdint.h>

#define B_ 4
#define T_ 2048
#define C_ 1024
#define H_ 16
#define D_ 64
#define M_ (B_*T_)      /* 8192 */
#define K_ C_           /* 1024 */

typedef unsigned short ushort_t;
typedef __bf16 bf16x8 __attribute__((ext_vector_type(8)));
typedef float  float4_ __attribute__((ext_vector_type(4)));
typedef ushort_t ushort4_ __attribute__((ext_vector_type(4)));

__device__ __forceinline__ ushort_t f2bf(float f) {
    union { float f; uint32_t u; } c; c.f = f;
    uint32_t u = c.u;
    uint32_t r = (u + 0x7FFFu + ((u >> 16) & 1u)) >> 16;
    return (ushort_t)r;
}
__device__ __forceinline__ float4_ f4zero() { float4_ z; z[0]=0.f; z[1]=0.f; z[2]=0.f; z[3]=0.f; return z; }

// async global->LDS, 16B per lane; LDS dest must be wave-uniform base + lane*16
#define GLDS16(gptr, lptr) \
    __builtin_amdgcn_global_load_lds((const __attribute__((address_space(1))) uint32_t*)(gptr), \
                                     (__attribute__((address_space(3))) uint32_t*)(lptr), 16, 0, 0)

// ---------------------------------------------------------------------------
// f32 -> bf16 conversion, 4 elements/thread
// ---------------------------------------------------------------------------
__global__ __launch_bounds__(256) void cvt_f32_bf16(const float* __restrict__ src,
                                                    ushort_t* __restrict__ dst) {
    const int i = (blockIdx.x * 256 + threadIdx.x) * 4;
    float4_ v = *(const float4_*)(src + i);
    ushort4_ o;
    #pragma unroll
    for (int e = 0; e < 4; e++) o[e] = f2bf(v[e]);
    *(ushort4_*)(dst + i) = o;
}

// fused 3-matrix cvt: wq|wk|wv (1M elements each) -> wcat [3072][1024]
__global__ __launch_bounds__(256) void cvt3_f32_bf16(const float* __restrict__ s0,
                                                     const float* __restrict__ s1,
                                                     const float* __restrict__ s2,
                                                     ushort_t* __restrict__ dst) {
    const int b = blockIdx.x;                       // 0..3071
    const float* src = (b < 1024) ? s0 : (b < 2048) ? s1 : s2;
    const int off = (b & 1023) * 1024 + threadIdx.x * 4;
    float4_ v = *(const float4_*)(src + off);
    ushort4_ o;
    #pragma unroll
    for (int e = 0; e < 4; e++) o[e] = f2bf(v[e]);
    *(ushort4_*)(dst + (size_t)b * 1024 + threadIdx.x * 4) = o;
}

// ---------------------------------------------------------------------------
// w_o f32 [1024(hd)][1024(c)] -> wot bf16 [1024(c)][1024(hd)]
// ---------------------------------------------------------------------------
__global__ __launch_bounds__(256) void transpose_wo(const float* __restrict__ wo,
                                                    ushort_t* __restrict__ wot) {
    __shared__ ushort_t tile[64][65];
    const int c0 = (blockIdx.x & 15) * 64;
    const int r0 = (blockIdx.x >> 4) * 64;   // hd tile base
    const int tid = threadIdx.x;
    const int row = tid >> 2;                // 64 rows, 4 threads/row
    const int col = (tid & 3) * 16;
    #pragma unroll
    for (int r = 0; r < 4; r++) {
        float4_ v = *(const float4_*)(wo + (size_t)(r0 + row) * 1024 + c0 + col + r * 4);
        #pragma unroll
        for (int e = 0; e < 4; e++) tile[row][col + r * 4 + e] = f2bf(v[e]);
    }
    __syncthreads();
    #pragma unroll
    for (int r = 0; r < 2; r++) {
        bf16x8 v;
        #pragma unroll
        for (int e = 0; e < 8; e++) v[e] = __builtin_bit_cast(__bf16, tile[col + r * 8 + e][row]);
        *(bf16x8*)(wot + (size_t)(c0 + row) * 1024 + r0 + col + r * 8) = v;
    }
}

// ---------------------------------------------------------------------------
// GEMM: C[M x N] = A[M x K] * Bt[N x K]^T  (bf16 in, fp32 acc)
// Staging via global_load_lds width=16 (m97 ladder step, 517->874 TF).
// MODE 0: Bt = Wcat [3072 x 1024]; epilogue scatters Q (x0.125) [nh][t][d],
//         K [nh][t][d], V transposed [nh][d][t]  (bf16 stores)
// MODE 1: Bt = wot [1024 x 1024]; f32 store to d_out
// ---------------------------------------------------------------------------
template<int MODE>
__global__ __launch_bounds__(256)
void gemm_bt(const ushort_t* __restrict__ A,
             const ushort_t* __restrict__ Bt,
             ushort_t* __restrict__ q_ws, ushort_t* __restrict__ k_ws,
             ushort_t* __restrict__ vt_ws, float* __restrict__ outp)
{
    __shared__ __align__(16) ushort_t As[128 * 32];
    __shared__ __align__(16) ushort_t Bs[128 * 32];
    const int tid = threadIdx.x;
    const int m0 = blockIdx.x * 128;
    const int n0 = blockIdx.y * 128;

    const int L    = tid & 63;
    const int wid  = tid >> 6;
    const int wr   = (wid >> 1) * 64;
    const int wc   = (wid & 1) * 64;
    const int quad = L >> 4;
    const int lc   = L & 15;

    float4_ acc[4][4];
    #pragma unroll
    for (int i = 0; i < 4; i++)
        #pragma unroll
        for (int j = 0; j < 4; j++) acc[i][j] = f4zero();

    const int loff0 = wid * 1024 + L * 16;   // per-lane byte offset = wave-base + lane*16
    for (int k0 = 0; k0 < K_; k0 += 32) {
        __syncthreads();
        #pragma unroll
        for (int r = 0; r < 2; r++) {
            const int off = loff0 + r * 4096;
            const int row = off >> 6;    // 64 B per tile row (32 bf16)
            const int col = off & 63;    // byte col
            const char* ga = (const char*)A  + (size_t)(m0 + row) * (K_ * 2) + k0 * 2 + col;
            const char* gb = (const char*)Bt + (size_t)(n0 + row) * (K_ * 2) + k0 * 2 + col;
            GLDS16(ga, (char*)As + off);
            GLDS16(gb, (char*)Bs + off);
        }
        __syncthreads();
        bf16x8 af[4], bfr[4];
        #pragma unroll
        for (int i = 0; i < 4; i++) {
            const int m = wr + i * 16 + lc;
            af[i]  = *(const bf16x8*)((const char*)As + m * 64 + quad * 16);
            const int n = wc + i * 16 + lc;
            bfr[i] = *(const bf16x8*)((const char*)Bs + n * 64 + quad * 16);
        }
        #pragma unroll
        for (int i = 0; i < 4; i++)
            #pragma unroll
            for (int j = 0; j < 4; j++)
                acc[i][j] = __builtin_amdgcn_mfma_f32_16x16x32_bf16(af[i], bfr[j], acc[i][j], 0, 0, 0);
    }

    // epilogue: C/D layout col=lane&15, row=quad*4+reg (m89-verified)
    const int mat = n0 >> 10;          // MODE 0: which of q/k/v
    const int nb  = n0 & 1023;
    #pragma unroll
    for (int i = 0; i < 4; i++) {
        #pragma unroll
        for (int j = 0; j < 4; j++) {
            #pragma unroll
            for (int rg = 0; rg < 4; rg++) {
                const int mg = m0 + wr + i * 16 + quad * 4 + rg;
                const float v = acc[i][j][rg];
                if (MODE == 1) {
                    const int cg = n0 + wc + j * 16 + lc;
                    outp[(size_t)mg * 1024 + cg] = v;          // f32 store
                } else {
                    const int ln = nb + wc + j * 16 + lc;
                    const int h = ln >> 6, d = ln & 63;
                    const int n = mg >> 11, t = mg & 2047;
                    const int nh = n * H_ + h;
                    if (mat == 0)      q_ws [((size_t)nh * T_ + t) * 64 + d] = f2bf(v * 0.125f);
                    else if (mat == 1) k_ws [((size_t)nh * T_ + t) * 64 + d] = f2bf(v);
                    else               vt_ws[((size_t)nh * 64 + d) * T_ + t] = f2bf(v);
                }
            }
        }
    }
}

// ---------------------------------------------------------------------------
// MFMA flash attention, transposed formulation (round-6, validated):
//   S^T = K Q^T ; O^T = V^T P^T ; per-lane scalar softmax state.
// This round: P^T writes packed 4x ds_write_b64 (was 16x ds_write_b16).
// LDS pitch 72 elements (144 B) — keeps quad-strided b128 reads ~conflict-free;
// NOTE: padding makes staging non-contiguous, so glds NOT usable here (m104).
// ---------------------------------------------------------------------------
#define KP 72   /* padded row pitch, elements */

__global__ __launch_bounds__(256)
void attn(const ushort_t* __restrict__ q_ws, const ushort_t* __restrict__ k_ws,
          const ushort_t* __restrict__ vt_ws, ushort_t* __restrict__ y_ws)
{
    __shared__ __align__(16) ushort_t Ks[64 * KP];      // [s][d], padded
    __shared__ __align__(16) ushort_t Vs[64 * KP];      // [d][s], padded
    __shared__ __align__(16) ushort_t Ps[4][16 * KP];   // per-wave P^T as [t][s]
    const int tid  = threadIdx.x;
    const int L    = tid & 63;
    const int w    = tid >> 6;
    const int quad = L >> 4, lc = L & 15;
    const int bid  = blockIdx.x;
    const int qt   = 31 - (bid & 31);    // heavy blocks first (tail balance)
    const int nh   = bid >> 5;
    const int n    = nh >> 4;
    const int tq0  = qt * 64 + w * 16;
    const int tg   = tq0 + lc;           // this lane's q-row

    // Q fragments (B-operand layout [n=t=lc][k=d=quad*8+j]):
    const ushort_t* qbase = q_ws + ((size_t)nh * T_ + tq0) * 64;
    const bf16x8 qf0 = *(const bf16x8*)(qbase + (size_t)lc * 64 + quad * 8);
    const bf16x8 qf1 = *(const bf16x8*)(qbase + (size_t)lc * 64 + quad * 8 + 32);

    float m_i = -1e30f, l_i = 0.f;       // per-lane scalars (q-row tg)
    float4_ o[4];                        // O^T C-layout: col=t (lane), row=d
    #pragma unroll
    for (int r = 0; r < 4; r++) o[r] = f4zero();

    const ushort_t* kbase = k_ws  + (size_t)nh * T_ * 64;   // [t][d]
    const ushort_t* vbase = vt_ws + (size_t)nh * 64 * T_;   // [d][t]
    ushort_t* pw = Ps[w];

    for (int st = 0; st <= qt; st++) {
        // stage K [s][d] and Vt [d][s] tiles; each thread 16 B x2 per array
        #pragma unroll
        for (int r = 0; r < 2; r++) {
            const int off = tid * 16 + r * 4096;   // logical offset in 64x128B tile
            const int row = off >> 7;
            const int col = off & 127;
            bf16x8 kv = *(const bf16x8*)((const char*)kbase + (size_t)(st * 64 + row) * 128 + col);
            bf16x8 vv = *(const bf16x8*)((const char*)vbase + (size_t)row * (T_ * 2) + st * 128 + col);
            *(bf16x8*)((char*)Ks + row * (KP * 2) + col) = kv;
            *(bf16x8*)((char*)Vs + row * (KP * 2) + col) = vv;
        }
        __syncthreads();

        // S^T = K Q^T: 4 s-blocks of 16; D[s][t]: row=quad*4+rg -> s, col=lc -> t
        float4_ s[4];
        #pragma unroll
        for (int sb = 0; sb < 4; sb++) {
            const int srow = sb * 16 + lc;
            const bf16x8 kf0 = *(const bf16x8*)((const char*)Ks + srow * (KP * 2) + quad * 16);
            const bf16x8 kf1 = *(const bf16x8*)((const char*)Ks + srow * (KP * 2) + 64 + quad * 16);
            float4_ a = f4zero();
            a = __builtin_amdgcn_mfma_f32_16x16x32_bf16(kf0, qf0, a, 0, 0, 0);
            a = __builtin_amdgcn_mfma_f32_16x16x32_bf16(kf1, qf1, a, 0, 0, 0);
            s[sb] = a;
        }
        if (st == qt) {   // causal mask on diagonal tile: s_global > t_global
            #pragma unroll
            for (int sb = 0; sb < 4; sb++)
                #pragma unroll
                for (int rg = 0; rg < 4; rg++) {
                    const int sg = st * 64 + sb * 16 + quad * 4 + rg;
                    if (sg > tg) s[sb][rg] = -1e30f;
                }
        }
        // online softmax, per-lane: 16 in-register scores for q-row tg
        float rm = -1e30f;
        #pragma unroll
        for (int sb = 0; sb < 4; sb++)
            #pragma unroll
            for (int rg = 0; rg < 4; rg++) rm = fmaxf(rm, s[sb][rg]);
        rm = fmaxf(rm, __shfl_xor(rm, 16));
        rm = fmaxf(rm, __shfl_xor(rm, 32));
        const float mn    = fmaxf(m_i, rm);
        const float alpha = __expf(m_i - mn);
        float rs = 0.f;
        #pragma unroll
        for (int sb = 0; sb < 4; sb++)
            #pragma unroll
            for (int rg = 0; rg < 4; rg++) {
                const float p = __expf(s[sb][rg] - mn);
                s[sb][rg] = p;
                rs += p;
            }
        rs += __shfl_xor(rs, 16);
        rs += __shfl_xor(rs, 32);
        l_i = l_i * alpha + rs;
        m_i = mn;
        #pragma unroll
        for (int db = 0; db < 4; db++)
            #pragma unroll
            for (int rg = 0; rg < 4; rg++) o[db][rg] *= alpha;

        // P^T -> LDS as [t][s]; rg-values are s-contiguous -> one b64 per sb
        #pragma unroll
        for (int sb = 0; sb < 4; sb++) {
            ushort4_ pk;
            #pragma unroll
            for (int rg = 0; rg < 4; rg++) pk[rg] = f2bf(s[sb][rg]);
            *(ushort4_*)(pw + lc * KP + sb * 16 + quad * 4) = pk;
        }

        // O^T += V^T P^T: A = Vs row d [k=s], B = Pb row t [k=s]
        const bf16x8 pa0 = *(const bf16x8*)((const char*)pw + lc * (KP * 2) + quad * 16);
        const bf16x8 pa1 = *(const bf16x8*)((const char*)pw + lc * (KP * 2) + 64 + quad * 16);
        #pragma unroll
        for (int db = 0; db < 4; db++) {
            const int d = db * 16 + lc;
            const bf16x8 vf0 = *(const bf16x8*)((const char*)Vs + d * (KP * 2) + quad * 16);
            const bf16x8 vf1 = *(const bf16x8*)((const char*)Vs + d * (KP * 2) + 64 + quad * 16);
            o[db] = __builtin_amdgcn_mfma_f32_16x16x32_bf16(vf0, pa0, o[db], 0, 0, 0);
            o[db] = __builtin_amdgcn_mfma_f32_16x16x32_bf16(vf1, pa1, o[db], 0, 0, 0);
        }
        __syncthreads();   // all waves done with Ks/Vs before next stage
    }

    // epilogue: O^T lane owns q-row tg; d = db*16 + quad*4 + rg (4 consecutive)
    const int h = nh & 15;
    const float inv = 1.f / l_i;
    ushort_t* yrow = y_ws + ((size_t)(n * T_ + tg)) * 1024 + h * 64;
    #pragma unroll
    for (int db = 0; db < 4; db++) {
        ushort4_ pk;
        #pragma unroll
        for (int rg = 0; rg < 4; rg++) pk[rg] = f2bf(o[db][rg] * inv);
        *(ushort4_*)(yrow + db * 16 + quad * 4) = pk;
    }
}

// ---------------------------------------------------------------------------
extern "C" void kernel_launch(void* const* d_in, const int* in_sizes, int n_in,
                              void* d_out, int out_size, void* d_ws, size_t ws_size,
                              hipStream_t stream) {
    (void)in_sizes; (void)n_in; (void)out_size; (void)ws_size;
    const float* x  = (const float*)d_in[0];
    const float* wq = (const float*)d_in[1];
    const float* wk = (const float*)d_in[2];
    const float* wv = (const float*)d_in[3];
    const float* wo = (const float*)d_in[4];
    char* ws = (char*)d_ws;
    const size_t MB = (size_t)1024 * 1024;
    ushort_t* x_bf  = (ushort_t*)(ws);            // 16 MB; reused as y after attn
    ushort_t* q_ws  = (ushort_t*)(ws + 16 * MB);  // 16 MB
    ushort_t* k_ws  = (ushort_t*)(ws + 32 * MB);  // 16 MB
    ushort_t* vt_ws = (ushort_t*)(ws + 48 * MB);  // 16 MB
    ushort_t* wcat  = (ushort_t*)(ws + 64 * MB);  // 6 MB  [3072][1024]
    ushort_t* wot   = (ushort_t*)(ws + 70 * MB);  // 2 MB  [1024(c)][1024(hd)]
    ushort_t* y_ws  = x_bf;                       // safe: attn never reads x_bf
    float*    outp  = (float*)d_out;              // f32 output

    cvt_f32_bf16<<<dim3(8192), dim3(256), 0, stream>>>(x, x_bf);
    cvt3_f32_bf16<<<dim3(3072), dim3(256), 0, stream>>>(wq, wk, wv, wcat);
    transpose_wo<<<dim3(256), dim3(256), 0, stream>>>(wo, wot);
    gemm_bt<0><<<dim3(64, 24), dim3(256), 0, stream>>>(x_bf, wcat, q_ws, k_ws, vt_ws, nullptr);
    attn<<<dim3(2048), dim3(256), 0, stream>>>(q_ws, k_ws, vt_ws, y_ws);
    gemm_bt<1><<<dim3(64, 8), dim3(256), 0, stream>>>(y_ws, wot, nullptr, nullptr, nullptr, outp);
}